// Round 13
// baseline (147.985 us; speedup 1.0000x reference)
//
#include <hip/hip_runtime.h>
#include <stdint.h>
#include <stddef.h>

#define Tdim 4096
#define Hdim 2048

typedef short short8 __attribute__((ext_vector_type(8)));
typedef float floatx4 __attribute__((ext_vector_type(4)));

// RNE fp32 -> bf16 bit pattern
__device__ __forceinline__ unsigned short f2bf(float f) {
  uint32_t u = __float_as_uint(f);
  u += 0x7fffu + ((u >> 16) & 1u);
  return (unsigned short)(u >> 16);
}

// async global->LDS, 16B per lane. LDS dest is wave-uniform base + lane*16.
__device__ __forceinline__ void load_lds16(const void* g, void* l) {
  __builtin_amdgcn_global_load_lds(
      (__attribute__((address_space(1))) unsigned int*)(uintptr_t)g,
      (__attribute__((address_space(3))) unsigned int*)l,
      16, 0, 0);
}

__device__ __forceinline__ float tanh_fast(float z) {
  // tanh(z) = 1 - 2/(exp(2z)+1); safe for all z
  float e = __expf(z + z);
  return 1.0f - __fdividef(2.0f, e + 1.0f);
}

// aligned LDS vector read (forces ds_read_b128)
__device__ __forceinline__ short8 lds_read8(const unsigned short* p) {
  return *(const short8*)__builtin_assume_aligned(p, 16);
}

// ---- convert + transpose b (HxH fp32, [k][n]) -> bt bf16 (N x K, [n][k]).
// x is no longer converted here (round 13): the GEMM stages A straight from
// fp32 x with in-register f2bf, deleting x's 84MB HBM round-trip. ----
__global__ __launch_bounds__(256) void cvt_kernel(const float* __restrict__ b,
                                                  unsigned short* __restrict__ bt) {
  __shared__ unsigned short tile[64 * 65];
  const int t = threadIdx.x;
  const int bj = blockIdx.x & 31;  // n block
  const int bi = blockIdx.x >> 5;  // k block
  {
    const int r0 = t >> 4, c4 = (t & 15) * 4;
#pragma unroll
    for (int p = 0; p < 4; ++p) {
      int r = r0 + p * 16;
      float4 v = *(const float4*)(b + (size_t)(bi * 64 + r) * Hdim + bj * 64 + c4);
      tile[r * 65 + c4 + 0] = f2bf(v.x);
      tile[r * 65 + c4 + 1] = f2bf(v.y);
      tile[r * 65 + c4 + 2] = f2bf(v.z);
      tile[r * 65 + c4 + 3] = f2bf(v.w);
    }
  }
  __syncthreads();
  {
    const int n = t >> 2, kq = (t & 3) * 16;
    union { unsigned short u[16]; uint4 v[2]; } o;
#pragma unroll
    for (int q = 0; q < 16; ++q) o.u[q] = tile[(kq + q) * 65 + n];
    uint4* dst = (uint4*)(bt + (size_t)(bj * 64 + n) * Hdim + bi * 64 + kq);
    dst[0] = o.v[0];
    dst[1] = o.v[1];
  }
}

// ---- GEMM (s = x @ b) with fused windowed-scan epilogue ----
// 128x128 tile, BK=64, 4 waves 2x2 of 64x64 (4x4 frags of 16x16x32 MFMA).
//
// Double-buffered staging (r12: 52.7 -> 47.5 us): loads for tile k+1 issue
// before compute of tile k; the barrier's vmcnt drain lands post-compute.
// Round 13: A is staged DIRECTLY from fp32 x -> registers -> f2bf ->
// ds_write (same XOR-swizzled layout; we control ds_write addresses).
// Deletes the cvt x round-trip (84 MB HBM). B stays DMA-staged bf16 from
// bt. __launch_bounds__(256,2) legalizes ~132 VGPRs without spill (r7's
// spill came from the allocator targeting 8 waves/SIMD; residency is
// grid-forced to 2 blocks/CU anyway).
// Pipeline order per iter: A fp32 loads issue -> B DMA issues -> compute ->
// f2bf+ds_write A (vmcnt waits only past the B-DMA count) -> barrier.
//
// LDS swizzle (BK=64, 3-bit XOR = full permutation of 8 chunks/row): slot
// (row, chunk c) holds global chunk c ^ (row&7); fragment reads XOR the
// same term -> SQ_LDS_BANK_CONFLICT ~0 (r5).
// XCD swizzle: grid (bm=32 fastest, bn=16) so XCD = bm%8 (r9: FETCH -40%).
// Warm rows: 8 extra A rows (t0-8..t0-1) so the scan warms up in-block
// (|a| <= 0.03125 -> influence of h_{t-8} < 1e-12); warm MFMA on waves 0,1.
// Epilogue: acc -> s_tile (136x129 fp32) -> 256 threads scan 128 cols x
// 2 half-chunks -> out. No s buffer in HBM.
__global__ __launch_bounds__(256, 2) void gemm_scan_kernel(const float* __restrict__ X,
                                                           const unsigned short* __restrict__ Bt,
                                                           const float* __restrict__ a_mat,
                                                           float* __restrict__ out) {
  // alignas(16) REQUIRED: otherwise union alignment is 4 and short8 LDS
  // reads split into 4x ds_read_b32 with 16-way conflicts (round-2: 263 us).
  __shared__ alignas(16) union SM {
    struct {
      unsigned short sA[2][128 * 64];   // 2 x 16 KB
      unsigned short sB[2][128 * 64];   // 2 x 16 KB
      unsigned short sAw[2][8 * 64];    // 2 x 1 KB
    } st;                      // 66 KB
    float s_tile[136 * 129];   // 68.6 KB; [row][col], pad 129
  } sm;

  const int tid = threadIdx.x;
  const int bm = blockIdx.x, bn = blockIdx.y;  // bm fastest -> XCD = bm%8
  const int wave = tid >> 6, lane = tid & 63;
  const int wm = (wave >> 1) * 64, wn = (wave & 1) * 64;
  const int l15 = lane & 15, quad = lane >> 4;
  const int l7 = l15 & 7;  // row&7 of the rows this lane reads fragments from

  // staging: thread tid owns LDS slot (row = tid>>3 + 32c, chunk = tid&7),
  // content = global chunk (tid&7)^(row&7); rows advance 32 (0 mod 8) per
  // c-chunk, so the XOR term is constant per thread.
  const int swz = ((tid & 7) ^ ((tid >> 3) & 7)) * 8;
  const float* aSrc = X + ((size_t)(bm * 128 + (tid >> 3)) * Hdim + swz);
  const unsigned short* bSrc = Bt + ((size_t)(bn * 128 + (tid >> 3)) * Hdim + swz);
  // warm rows handled by wave 3: lane -> row=lane>>3 (8 rows), chunk=lane&7
  const int tw0 = (bm > 0) ? bm * 128 - 8 : 0;  // clamp keeps address valid; bm==0 warm unused
  const int wswz = ((lane & 7) ^ ((lane >> 3) & 7)) * 8;
  const float* wSrc = X + ((size_t)(tw0 + (lane >> 3)) * Hdim + wswz);

  floatx4 acc[4][4] = {};
  floatx4 accw[4] = {};
  float4 raf[4][2];  // A fp32 tile in flight (32 VGPRs)
  float4 rwf[2];     // warm rows (wave 3 only)

  // issue A fp32 loads for tile k0 (held in regs across compute)
  auto loadA = [&](int k0) {
#pragma unroll
    for (int c = 0; c < 4; ++c) {
      const float* p = aSrc + (size_t)c * 32 * Hdim + k0;
      raf[c][0] = ((const float4*)p)[0];
      raf[c][1] = ((const float4*)p)[1];
    }
    if (wave == 3) {
      const float* q = wSrc + k0;
      rwf[0] = ((const float4*)q)[0];
      rwf[1] = ((const float4*)q)[1];
    }
  };

  // issue B DMA for tile k0 into buffer buf
  auto dmaB = [&](int buf, int k0) {
    unsigned short* bDst = &sm.st.sB[buf][tid * 8];
#pragma unroll
    for (int c = 0; c < 4; ++c)
      load_lds16(bSrc + (size_t)c * 32 * Hdim + k0, bDst + c * 2048);
  };

  // convert + write the in-flight A tile into buffer buf
  auto writeA = [&](int buf) {
#pragma unroll
    for (int c = 0; c < 4; ++c) {
      short8 v;
      v[0] = f2bf(raf[c][0].x); v[1] = f2bf(raf[c][0].y);
      v[2] = f2bf(raf[c][0].z); v[3] = f2bf(raf[c][0].w);
      v[4] = f2bf(raf[c][1].x); v[5] = f2bf(raf[c][1].y);
      v[6] = f2bf(raf[c][1].z); v[7] = f2bf(raf[c][1].w);
      *(short8*)__builtin_assume_aligned(&sm.st.sA[buf][tid * 8 + c * 2048], 16) = v;
    }
    if (wave == 3) {
      short8 v;
      v[0] = f2bf(rwf[0].x); v[1] = f2bf(rwf[0].y);
      v[2] = f2bf(rwf[0].z); v[3] = f2bf(rwf[0].w);
      v[4] = f2bf(rwf[1].x); v[5] = f2bf(rwf[1].y);
      v[6] = f2bf(rwf[1].z); v[7] = f2bf(rwf[1].w);
      *(short8*)__builtin_assume_aligned(&sm.st.sAw[buf][lane * 8], 16) = v;
    }
  };

  // compute tile from buffer buf
  auto compute = [&](int buf) {
#pragma unroll
    for (int kk = 0; kk < 64; kk += 32) {
      const int coff = (((kk >> 3) + quad) ^ l7) * 8;
      short8 av[4], bv[4];
#pragma unroll
      for (int i = 0; i < 4; ++i)
        av[i] = lds_read8(&sm.st.sA[buf][(wm + i * 16 + l15) * 64 + coff]);
#pragma unroll
      for (int j = 0; j < 4; ++j)
        bv[j] = lds_read8(&sm.st.sB[buf][(wn + j * 16 + l15) * 64 + coff]);
#pragma unroll
      for (int i = 0; i < 4; ++i)
#pragma unroll
        for (int j = 0; j < 4; ++j)
          acc[i][j] = __builtin_amdgcn_mfma_f32_16x16x32_bf16(av[i], bv[j], acc[i][j], 0, 0, 0);
      if (wave < 2) {  // warm rows: frag read + MFMA on waves 0,1 only
        short8 aw = lds_read8(&sm.st.sAw[buf][l7 * 64 + coff]);
#pragma unroll
        for (int j = 0; j < 4; ++j)
          accw[j] = __builtin_amdgcn_mfma_f32_16x16x32_bf16(aw, bv[j], accw[j], 0, 0, 0);
      }
    }
  };

  // prologue: tile 0 -> buf 0
  loadA(0);
  dmaB(0, 0);
  writeA(0);       // waits on the A loads; B DMA drains at the barrier
  __syncthreads();

  // main loop, unrolled x2 so buffer indices are compile-time
  for (int it = 0; it < 32; it += 2) {
    loadA((it + 1) * 64);            // A fp32 loads in flight during compute
    dmaB(1, (it + 1) * 64);          // B DMA in flight during compute
    compute(0);
    writeA(1);                       // vmcnt waits only past the B-DMA count
    __syncthreads();                 // drain lands AFTER compute
    if (it + 2 < 32) {
      loadA((it + 2) * 64);
      dmaB(0, (it + 2) * 64);
    }
    compute(1);
    if (it + 2 < 32) writeA(0);
    __syncthreads();
  }

  // ---- epilogue: registers -> s_tile (C/D layout: col=lane&15, row=quad*4+r) ----
  if (wave < 2 && quad < 2) {  // warm rows idx 0..7 (valid m = 0..7 only)
#pragma unroll
    for (int j = 0; j < 4; ++j)
#pragma unroll
      for (int r = 0; r < 4; ++r)
        sm.s_tile[(quad * 4 + r) * 129 + wn + j * 16 + l15] = accw[j][r];
  }
#pragma unroll
  for (int i = 0; i < 4; ++i)
#pragma unroll
    for (int j = 0; j < 4; ++j)
#pragma unroll
      for (int r = 0; r < 4; ++r)
        sm.s_tile[(8 + wm + i * 16 + quad * 4 + r) * 129 + wn + j * 16 + l15] = acc[i][j][r];
  __syncthreads();

  // ---- windowed scan: 256 threads = 128 cols x 2 half-chunks of 64 rows ----
  const int col = tid & 127;
  const int half = tid >> 7;
  const float aj = a_mat[bn * 128 + col];
  float h = 0.0f;
  const int row0 = 8 + half * 64;
  if (!(bm == 0 && half == 0)) {
#pragma unroll
    for (int r = row0 - 8; r < row0; ++r)  // warm-up (discarded outputs)
      h = tanh_fast(fmaf(aj, h, sm.s_tile[r * 129 + col]));
  }
  const size_t gbase = (size_t)(bm * 128 + half * 64) * Hdim + bn * 128 + col;
#pragma unroll 4
  for (int r2 = 0; r2 < 64; ++r2) {
    h = tanh_fast(fmaf(aj, h, sm.s_tile[(row0 + r2) * 129 + col]));
    out[gbase + (size_t)r2 * Hdim] = h;
  }
}

extern "C" void kernel_launch(void* const* d_in, const int* in_sizes, int n_in,
                              void* d_out, int out_size, void* d_ws, size_t ws_size,
                              hipStream_t stream) {
  const float* x = (const float*)d_in[0];
  const float* a = (const float*)d_in[1];
  const float* b = (const float*)d_in[2];
  float* out = (float*)d_out;

  unsigned short* btb = (unsigned short*)d_ws;              // 8.4 MB

  hipLaunchKernelGGL(cvt_kernel, dim3((Hdim / 64) * (Hdim / 64)), dim3(256), 0, stream,
                     b, btb);
  // grid: x = bm (32, fastest -> XCD = bm%8), y = bn (16)
  hipLaunchKernelGGL(gemm_scan_kernel, dim3(Tdim / 128, Hdim / 128), dim3(256), 0, stream,
                     x, btb, a, out);
}

// Round 14
// 142.504 us; speedup vs baseline: 1.0385x; 1.0385x over previous
//
#include <hip/hip_runtime.h>
#include <stdint.h>
#include <stddef.h>

#define Tdim 4096
#define Hdim 2048

typedef short short8 __attribute__((ext_vector_type(8)));
typedef float floatx4 __attribute__((ext_vector_type(4)));

// RNE fp32 -> bf16 bit pattern
__device__ __forceinline__ unsigned short f2bf(float f) {
  uint32_t u = __float_as_uint(f);
  u += 0x7fffu + ((u >> 16) & 1u);
  return (unsigned short)(u >> 16);
}

// async global->LDS, 16B per lane. LDS dest is wave-uniform base + lane*16.
__device__ __forceinline__ void load_lds16(const void* g, void* l) {
  __builtin_amdgcn_global_load_lds(
      (__attribute__((address_space(1))) unsigned int*)(uintptr_t)g,
      (__attribute__((address_space(3))) unsigned int*)l,
      16, 0, 0);
}

__device__ __forceinline__ float tanh_fast(float z) {
  // tanh(z) = 1 - 2/(exp(2z)+1); safe for all z
  float e = __expf(z + z);
  return 1.0f - __fdividef(2.0f, e + 1.0f);
}

// aligned LDS vector read (forces ds_read_b128)
__device__ __forceinline__ short8 lds_read8(const unsigned short* p) {
  return *(const short8*)__builtin_assume_aligned(p, 16);
}

// ---- fused convert: blocks [0,2048) cast x -> bf16 (16 elems/thread);
// blocks [2048,3072) transpose+cast b (HxH fp32,[k][n]) -> bt bf16 (N x K).
// r13 lesson: conversion must stay OFF the GEMM critical loop — in-loop
// f2bf displaced MFMA issue (MfmaUtil 32->21). Streaming kernel is cheap. ----
__global__ __launch_bounds__(256) void cvt_kernel(const float* __restrict__ x,
                                                  const float* __restrict__ b,
                                                  unsigned short* __restrict__ xbf,
                                                  unsigned short* __restrict__ bt) {
  __shared__ unsigned short tile[64 * 65];
  const int t = threadIdx.x;
  if (blockIdx.x < 2048) {
    size_t i = ((size_t)blockIdx.x * 256 + t) * 16;
#pragma unroll
    for (int h = 0; h < 2; ++h) {
      float4 f0 = *(const float4*)(x + i + h * 8);
      float4 f1 = *(const float4*)(x + i + h * 8 + 4);
      union { unsigned short u[8]; uint4 v; } o;
      o.u[0] = f2bf(f0.x); o.u[1] = f2bf(f0.y); o.u[2] = f2bf(f0.z); o.u[3] = f2bf(f0.w);
      o.u[4] = f2bf(f1.x); o.u[5] = f2bf(f1.y); o.u[6] = f2bf(f1.z); o.u[7] = f2bf(f1.w);
      *(uint4*)(xbf + i + h * 8) = o.v;
    }
    return;
  }
  const int tb = blockIdx.x - 2048;
  const int bj = tb & 31;  // n block
  const int bi = tb >> 5;  // k block
  {
    const int r0 = t >> 4, c4 = (t & 15) * 4;
#pragma unroll
    for (int p = 0; p < 4; ++p) {
      int r = r0 + p * 16;
      float4 v = *(const float4*)(b + (size_t)(bi * 64 + r) * Hdim + bj * 64 + c4);
      tile[r * 65 + c4 + 0] = f2bf(v.x);
      tile[r * 65 + c4 + 1] = f2bf(v.y);
      tile[r * 65 + c4 + 2] = f2bf(v.z);
      tile[r * 65 + c4 + 3] = f2bf(v.w);
    }
  }
  __syncthreads();
  {
    const int n = t >> 2, kq = (t & 3) * 16;
    union { unsigned short u[16]; uint4 v[2]; } o;
#pragma unroll
    for (int q = 0; q < 16; ++q) o.u[q] = tile[(kq + q) * 65 + n];
    uint4* dst = (uint4*)(bt + (size_t)(bj * 64 + n) * Hdim + bi * 64 + kq);
    dst[0] = o.v[0];
    dst[1] = o.v[1];
  }
}

// ---- GEMM (s = x @ b) with fused windowed-scan epilogue (r12 structure,
// the session best: 47.5 us) ----
// 128x128 tile, BK=64, 4 waves 2x2 of 64x64 (4x4 frags of 16x16x32 MFMA).
//
// DOUBLE-BUFFERED DMA staging: issue global_load_lds for tile k+1 into
// buffer B, THEN compute tile k from buffer A, THEN one barrier — the
// vmcnt(0) drain lands after ~620 cyc of MFMA covered the L2 latency
// (single-buffered rounds drained BEFORE compute: MfmaUtil pinned ~29%).
// DMA staging costs zero data-VGPRs (r7 register prefetch spilled 247MB;
// r13 in-loop fp32->bf16 conversion displaced MFMA issue with VALU).
//
// LDS swizzle (BK=64, 3-bit XOR = full permutation of 8 chunks/row): slot
// (row, chunk c) holds global chunk c ^ (row&7); swizzle applied on the
// global fetch column (wave-uniform contiguous DMA dest preserved);
// fragment reads XOR the same term -> SQ_LDS_BANK_CONFLICT ~0.
// (BK=128 tried in r10/r11: drain halving was exactly cancelled by 4-bit
// swizzle aliasing / extra conflict cost — net zero.)
//
// XCD swizzle: grid (bm=32 fastest, bn=16) so XCD = bm%8; per-XCD A
// working set 2MB, L2-resident -> FETCH 69.7 -> 41.5 MB (r9).
//
// Warm rows: 8 extra A rows (t0-8..t0-1) so the scan warms up in-block
// (|a| <= 0.03125 -> influence of h_{t-8} < 1e-12); warm frag+MFMA on
// waves 0,1 only. Epilogue: acc -> s_tile (136x129 fp32, pad 129) ->
// 256 threads scan 128 cols x 2 half-chunks -> out. No s buffer in HBM.
__global__ __launch_bounds__(256) void gemm_scan_kernel(const unsigned short* __restrict__ A,
                                                        const unsigned short* __restrict__ Bt,
                                                        const float* __restrict__ a_mat,
                                                        float* __restrict__ out) {
  // alignas(16) REQUIRED: otherwise union alignment is 4 and short8 LDS
  // reads split into 4x ds_read_b32 with 16-way conflicts (round-2: 263 us).
  __shared__ alignas(16) union SM {
    struct {
      unsigned short sA[2][128 * 64];   // 2 x 16 KB
      unsigned short sB[2][128 * 64];   // 2 x 16 KB
      unsigned short sAw[2][8 * 64];    // 2 x 1 KB
    } st;                      // 66 KB
    float s_tile[136 * 129];   // 68.6 KB; [row][col], pad 129
  } sm;

  const int tid = threadIdx.x;
  const int bm = blockIdx.x, bn = blockIdx.y;  // bm fastest -> XCD = bm%8
  const int wave = tid >> 6, lane = tid & 63;
  const int wm = (wave >> 1) * 64, wn = (wave & 1) * 64;
  const int l15 = lane & 15, quad = lane >> 4;
  const int l7 = l15 & 7;  // row&7 of the rows this lane reads fragments from

  // staging: thread tid fills LDS slot (row = tid>>3 + 32c, chunk = tid&7)
  // and fetches global chunk (tid&7)^(row&7); rows advance 32 (0 mod 8) per
  // c-chunk, so the XOR term is constant per thread.
  const int swz = ((tid & 7) ^ ((tid >> 3) & 7)) * 8;
  const unsigned short* aSrc = A + ((size_t)(bm * 128 + (tid >> 3)) * Hdim + swz);
  const unsigned short* bSrc = Bt + ((size_t)(bn * 128 + (tid >> 3)) * Hdim + swz);
  // warm rows staged by wave 3: lane -> row=lane>>3 (8 rows), chunk=lane&7
  const int tw0 = (bm > 0) ? bm * 128 - 8 : 0;  // clamp keeps address valid; bm==0 warm unused
  const int wswz = ((lane & 7) ^ ((lane >> 3) & 7)) * 8;
  const unsigned short* wSrc = A + ((size_t)(tw0 + (lane >> 3)) * Hdim + wswz);

  floatx4 acc[4][4] = {};
  floatx4 accw[4] = {};

  // stage tile (k0) into buffer `buf`
  auto stage = [&](int buf, int k0) {
    unsigned short* aDst = &sm.st.sA[buf][tid * 8];
    unsigned short* bDst = &sm.st.sB[buf][tid * 8];
#pragma unroll
    for (int c = 0; c < 4; ++c)
      load_lds16(aSrc + (size_t)c * 32 * Hdim + k0, aDst + c * 2048);
#pragma unroll
    for (int c = 0; c < 4; ++c)
      load_lds16(bSrc + (size_t)c * 32 * Hdim + k0, bDst + c * 2048);
    if (wave == 3) load_lds16(wSrc + k0, &sm.st.sAw[buf][lane * 8]);
  };

  // compute from buffer `buf`
  auto compute = [&](int buf) {
#pragma unroll
    for (int kk = 0; kk < 64; kk += 32) {
      const int coff = (((kk >> 3) + quad) ^ l7) * 8;
      short8 av[4], bv[4];
#pragma unroll
      for (int i = 0; i < 4; ++i)
        av[i] = lds_read8(&sm.st.sA[buf][(wm + i * 16 + l15) * 64 + coff]);
#pragma unroll
      for (int j = 0; j < 4; ++j)
        bv[j] = lds_read8(&sm.st.sB[buf][(wn + j * 16 + l15) * 64 + coff]);
#pragma unroll
      for (int i = 0; i < 4; ++i)
#pragma unroll
        for (int j = 0; j < 4; ++j)
          acc[i][j] = __builtin_amdgcn_mfma_f32_16x16x32_bf16(av[i], bv[j], acc[i][j], 0, 0, 0);
      if (wave < 2) {  // warm rows: frag read + MFMA on waves 0,1 only
        short8 aw = lds_read8(&sm.st.sAw[buf][l7 * 64 + coff]);
#pragma unroll
        for (int j = 0; j < 4; ++j)
          accw[j] = __builtin_amdgcn_mfma_f32_16x16x32_bf16(aw, bv[j], accw[j], 0, 0, 0);
      }
    }
  };

  // prologue: tile 0 -> buf 0
  stage(0, 0);
  __syncthreads();
  // main loop, unrolled x2 so buffer indices are compile-time
  for (int it = 0; it < 32; it += 2) {
    stage(1, (it + 1) * 64);          // loads in flight during compute
    compute(0);
    __syncthreads();                  // drain lands AFTER compute
    if (it + 2 < 32) stage(0, (it + 2) * 64);
    compute(1);
    __syncthreads();
  }

  // ---- epilogue: registers -> s_tile (C/D layout: col=lane&15, row=quad*4+r) ----
  if (wave < 2 && quad < 2) {  // warm rows idx 0..7 (valid m = 0..7 only)
#pragma unroll
    for (int j = 0; j < 4; ++j)
#pragma unroll
      for (int r = 0; r < 4; ++r)
        sm.s_tile[(quad * 4 + r) * 129 + wn + j * 16 + l15] = accw[j][r];
  }
#pragma unroll
  for (int i = 0; i < 4; ++i)
#pragma unroll
    for (int j = 0; j < 4; ++j)
#pragma unroll
      for (int r = 0; r < 4; ++r)
        sm.s_tile[(8 + wm + i * 16 + quad * 4 + r) * 129 + wn + j * 16 + l15] = acc[i][j][r];
  __syncthreads();

  // ---- windowed scan: 256 threads = 128 cols x 2 half-chunks of 64 rows ----
  const int col = tid & 127;
  const int half = tid >> 7;
  const float aj = a_mat[bn * 128 + col];
  float h = 0.0f;
  const int row0 = 8 + half * 64;
  if (!(bm == 0 && half == 0)) {
#pragma unroll
    for (int r = row0 - 8; r < row0; ++r)  // warm-up (discarded outputs)
      h = tanh_fast(fmaf(aj, h, sm.s_tile[r * 129 + col]));
  }
  const size_t gbase = (size_t)(bm * 128 + half * 64) * Hdim + bn * 128 + col;
#pragma unroll 4
  for (int r2 = 0; r2 < 64; ++r2) {
    h = tanh_fast(fmaf(aj, h, sm.s_tile[(row0 + r2) * 129 + col]));
    out[gbase + (size_t)r2 * Hdim] = h;
  }
}

extern "C" void kernel_launch(void* const* d_in, const int* in_sizes, int n_in,
                              void* d_out, int out_size, void* d_ws, size_t ws_size,
                              hipStream_t stream) {
  const float* x = (const float*)d_in[0];
  const float* a = (const float*)d_in[1];
  const float* b = (const float*)d_in[2];
  float* out = (float*)d_out;

  unsigned short* ws = (unsigned short*)d_ws;
  unsigned short* xbf = ws;                                 // 16.8 MB
  unsigned short* btb = xbf + (size_t)Tdim * Hdim;          // 8.4 MB

  hipLaunchKernelGGL(cvt_kernel, dim3(2048 + (Hdim / 64) * (Hdim / 64)), dim3(256), 0, stream,
                     x, b, xbf, btb);
  // grid: x = bm (32, fastest -> XCD = bm%8), y = bn (16)
  hipLaunchKernelGGL(gemm_scan_kernel, dim3(Tdim / 128, Hdim / 128), dim3(256), 0, stream,
                     xbf, btb, a, out);
}